// Round 6
// baseline (530.593 us; speedup 1.0000x reference)
//
#include <hip/hip_runtime.h>
#include <math.h>

#define B_ 16
#define L_ 1024
#define H_ 8
#define U_ 35

typedef float f32x4 __attribute__((ext_vector_type(4)));
typedef short bf16x8 __attribute__((ext_vector_type(8)));

__device__ __forceinline__ unsigned short f2bf(float x) {
    unsigned int u = __float_as_uint(x);
    u += 0x7FFFu + ((u >> 16) & 1u);      // round-to-nearest-even
    return (unsigned short)(u >> 16);
}
__device__ __forceinline__ float bf2f(unsigned short b) {
    return __uint_as_float(((unsigned int)b) << 16);
}

#define MFMA(a, b, c) __builtin_amdgcn_mfma_f32_16x16x32_bf16((a), (b), (c), 0, 0, 0)

// ---------------- workspace layout (float-element offsets) ----------------
#define OFF_V      ((size_t)0)           // 8388608 f
#define OFF_QHI    ((size_t)8388608)     // 4194304
#define OFF_QLO    ((size_t)12582912)    // 4194304
#define OFF_CTXP   OFF_QHI               // ctx partials alias q_hi (dead after scores)
#define OFF_KHI    ((size_t)16777216)    // 4194304
#define OFF_KLO    ((size_t)20971520)    // 4194304
#define OFF_S      ((size_t)25165824)    // 4587520
#define OFF_WQH    OFF_S                 // W splits alias S (dead before scores)
#define OFF_WQL    ((size_t)(OFF_S + 131072))
#define OFF_WKH    ((size_t)(OFF_S + 262144))
#define OFF_WKL    ((size_t)(OFF_S + 393216))
#define OFF_WVH    ((size_t)(OFF_S + 524288))
#define OFF_WVL    ((size_t)(OFF_S + 655360))
#define OFF_M      ((size_t)29753344)    // 131072
#define OFF_KMEAN  ((size_t)29884416)    // 8192
#define OFF_VMEAN  ((size_t)29892608)    // 8192
#define OFF_CTXD   ((size_t)29900800)    // 286720 (ctx - vmean diffs)
#define OFF_IDX    ((size_t)30187520)    // 4480
#define OFF_OBASE  ((size_t)30192000)    // 8192 (per-b base output row)
// end ~30.2M f = ~121 MB

// ---------------------------------------------------------------
// split Wq/Wk/Wv fp32 -> hi/lo bf16; grid 3072 x 256
// ---------------------------------------------------------------
__global__ __launch_bounds__(256) void split_w3(
    const float* __restrict__ Wq, const float* __restrict__ Wk,
    const float* __restrict__ Wv,
    unsigned short* __restrict__ wqh, unsigned short* __restrict__ wql,
    unsigned short* __restrict__ wkh, unsigned short* __restrict__ wkl,
    unsigned short* __restrict__ wvh, unsigned short* __restrict__ wvl)
{
    const int w = blockIdx.x >> 10;
    const int i = (blockIdx.x & 1023) * 256 + threadIdx.x;
    const float* W = (w == 0) ? Wq : (w == 1) ? Wk : Wv;
    unsigned short* hi = (w == 0) ? wqh : (w == 1) ? wkh : wvh;
    unsigned short* lo = (w == 0) ? wql : (w == 1) ? wkl : wvl;
    float x = W[i];
    unsigned short h = f2bf(x);
    hi[i] = h;
    lo[i] = f2bf(x - bf2f(h));
}

// ---------------------------------------------------------------
// bf16x2 MFMA GEMM: C[m,n] = sum_k A[m,k]*W[n,k] + bias[n]
// ---------------------------------------------------------------
__global__ __launch_bounds__(256) void gemm_mfma(
    const float* __restrict__ A,
    const unsigned short* __restrict__ Whi, const unsigned short* __restrict__ Wlo,
    const float* __restrict__ bias,
    float* __restrict__ outf,
    unsigned short* __restrict__ ohi, unsigned short* __restrict__ olo,
    const int head_layout)
{
    __shared__ unsigned short Ah[128][40];
    __shared__ unsigned short Al[128][40];
    __shared__ unsigned short Bh[128][40];
    __shared__ unsigned short Bl[128][40];
    const int tid = threadIdx.x, lane = tid & 63, wave = tid >> 6;
    const int m0 = blockIdx.x * 128, n0 = blockIdx.y * 128;
    const int wm = (wave >> 1) * 64, wn = (wave & 1) * 64;

    f32x4 zero4 = {0.f, 0.f, 0.f, 0.f};
    f32x4 acc[4][4];
#pragma unroll
    for (int i = 0; i < 4; i++)
#pragma unroll
        for (int j = 0; j < 4; j++) acc[i][j] = zero4;

    const int ar = tid >> 3, ac = (tid & 7) * 4;
    const int br = tid >> 2, bc = (tid & 3) * 8;
    const int kc = (lane >> 4) * 8;
    const int fr = lane & 15;

    for (int k0 = 0; k0 < 512; k0 += 32) {
        if (k0) __syncthreads();
#pragma unroll
        for (int p = 0; p < 4; ++p) {
            float4 a4 = *(const float4*)(A + (size_t)(m0 + ar + p * 32) * 512 + k0 + ac);
            ushort4 h4, l4;
            h4.x = f2bf(a4.x); l4.x = f2bf(a4.x - bf2f(h4.x));
            h4.y = f2bf(a4.y); l4.y = f2bf(a4.y - bf2f(h4.y));
            h4.z = f2bf(a4.z); l4.z = f2bf(a4.z - bf2f(h4.z));
            h4.w = f2bf(a4.w); l4.w = f2bf(a4.w - bf2f(h4.w));
            *(ushort4*)&Ah[ar + p * 32][ac] = h4;
            *(ushort4*)&Al[ar + p * 32][ac] = l4;
        }
#pragma unroll
        for (int p = 0; p < 2; ++p) {
            size_t off = (size_t)(n0 + br + p * 64) * 512 + k0 + bc;
            *(uint4*)&Bh[br + p * 64][bc] = *(const uint4*)(Whi + off);
            *(uint4*)&Bl[br + p * 64][bc] = *(const uint4*)(Wlo + off);
        }
        __syncthreads();

        bf16x8 ah[4], al[4];
#pragma unroll
        for (int mi = 0; mi < 4; ++mi) {
            int row = wm + mi * 16 + fr;
            ah[mi] = *(bf16x8*)&Ah[row][kc];
            al[mi] = *(bf16x8*)&Al[row][kc];
        }
#pragma unroll
        for (int ni = 0; ni < 4; ++ni) {
            int rn = wn + ni * 16 + fr;
            bf16x8 bh8 = *(bf16x8*)&Bh[rn][kc];
            bf16x8 bl8 = *(bf16x8*)&Bl[rn][kc];
#pragma unroll
            for (int mi = 0; mi < 4; ++mi) {
                acc[mi][ni] = MFMA(ah[mi], bh8, acc[mi][ni]);
                acc[mi][ni] = MFMA(ah[mi], bl8, acc[mi][ni]);
                acc[mi][ni] = MFMA(al[mi], bh8, acc[mi][ni]);
            }
        }
    }

    const int col = lane & 15, rq = (lane >> 4) * 4;
#pragma unroll
    for (int ni = 0; ni < 4; ++ni) {
        int n = n0 + wn + ni * 16 + col;
        float bn = bias[n];
#pragma unroll
        for (int mi = 0; mi < 4; ++mi) {
#pragma unroll
            for (int r = 0; r < 4; ++r) {
                int m = m0 + wm + mi * 16 + rq + r;
                float val = acc[mi][ni][r] + bn;
                if (head_layout) {
                    size_t off = ((size_t)((m >> 10) * H_ + (n >> 6)) * L_ + (m & 1023)) * 64 + (n & 63);
                    if (outf) outf[off] = val;
                    if (ohi) {
                        unsigned short h = f2bf(val);
                        ohi[off] = h;
                        olo[off] = f2bf(val - bf2f(h));
                    }
                } else {
                    outf[(size_t)m * 512 + n] = val;
                }
            }
        }
    }
}

// ---------------------------------------------------------------
// fused means: blocks 0..127 -> kmean (from k hi/lo), 128..255 -> vmean (fp32)
// ---------------------------------------------------------------
__global__ __launch_bounds__(256) void means_fused(
    const unsigned short* __restrict__ khi, const unsigned short* __restrict__ klo,
    const float* __restrict__ v, float* __restrict__ kmean, float* __restrict__ vmean)
{
    const int which = blockIdx.x >> 7;
    const int bh = blockIdx.x & 127;
    const int d = threadIdx.x & 63, g = threadIdx.x >> 6;
    __shared__ float red[4][64];
    float s = 0.f;
    if (which == 0) {
        size_t base = ((size_t)bh * L_ + g * 256) * 64 + d;
#pragma unroll 8
        for (int l = 0; l < 256; l++) {
            size_t o = base + (size_t)l * 64;
            s += bf2f(khi[o]) + bf2f(klo[o]);
        }
    } else {
        const float* p = v + ((size_t)bh * L_ + g * 256) * 64 + d;
#pragma unroll 8
        for (int l = 0; l < 256; l++) s += p[(size_t)l * 64];
    }
    red[g][d] = s;
    __syncthreads();
    if (threadIdx.x < 64) {
        const int dd = threadIdx.x;
        float m = (red[0][dd] + red[1][dd] + red[2][dd] + red[3][dd]) * (1.0f / 1024.0f);
        (which == 0 ? kmean : vmean)[(size_t)bh * 64 + dd] = m;
    }
}

// ---------------------------------------------------------------
// M[l] = max_k(q_l . k_k) - q_l . kmean via bf16x2 MFMA, reg-prefetch staging
// grid (128 bh, 16 qt): linid = bh + 128*qt -> xcd = bh%8, so all 16
// q-tiles of a bh land on one XCD and share its K tiles in that L2.
// ---------------------------------------------------------------
__global__ __launch_bounds__(256) void qk_rowmax_mfma(
    const unsigned short* __restrict__ qhi, const unsigned short* __restrict__ qlo,
    const unsigned short* __restrict__ khi, const unsigned short* __restrict__ klo,
    const float* __restrict__ kmean, float* __restrict__ Mout)
{
    __shared__ unsigned short Qh[64][72], Ql[64][72];
    __shared__ unsigned short Kh[128][72], Kl[128][72];
    __shared__ float Mred[64][4];
    __shared__ float km[64];
    const int bh = blockIdx.x, q0 = blockIdx.y * 64;
    const int tid = threadIdx.x, lane = tid & 63, wave = tid >> 6;

    if (tid < 64) km[tid] = kmean[bh * 64 + tid];
    {
        int r = tid >> 2, c = (tid & 3) * 16;
        size_t off = ((size_t)bh * L_ + q0 + r) * 64 + c;
        *(uint4*)&Qh[r][c]     = *(const uint4*)(qhi + off);
        *(uint4*)&Qh[r][c + 8] = *(const uint4*)(qhi + off + 8);
        *(uint4*)&Ql[r][c]     = *(const uint4*)(qlo + off);
        *(uint4*)&Ql[r][c + 8] = *(const uint4*)(qlo + off + 8);
    }

    float rmax[4][4];
#pragma unroll
    for (int mi = 0; mi < 4; ++mi)
#pragma unroll
        for (int r = 0; r < 4; ++r) rmax[mi][r] = -INFINITY;

    const size_t kb = (size_t)bh * L_ * 64;
    const int sr = tid >> 2, sc = (tid & 3) * 16;
    const int fr = lane & 15;
    f32x4 zero4 = {0.f, 0.f, 0.f, 0.f};

    // register prefetch of tile 0
    uint4 ph0a, ph0b, pl0a, pl0b, ph1a, ph1b, pl1a, pl1b;
    {
        size_t off = kb + (size_t)sr * 64 + sc;
        ph0a = *(const uint4*)(khi + off);       ph0b = *(const uint4*)(khi + off + 8);
        pl0a = *(const uint4*)(klo + off);       pl0b = *(const uint4*)(klo + off + 8);
        size_t off2 = off + 4096;
        ph1a = *(const uint4*)(khi + off2);      ph1b = *(const uint4*)(khi + off2 + 8);
        pl1a = *(const uint4*)(klo + off2);      pl1b = *(const uint4*)(klo + off2 + 8);
    }

    for (int kt = 0; kt < 8; ++kt) {
        __syncthreads();   // previous tile's readers done (also fences Q/km stage)
        *(uint4*)&Kh[sr][sc]          = ph0a;  *(uint4*)&Kh[sr][sc + 8]      = ph0b;
        *(uint4*)&Kl[sr][sc]          = pl0a;  *(uint4*)&Kl[sr][sc + 8]      = pl0b;
        *(uint4*)&Kh[sr + 64][sc]     = ph1a;  *(uint4*)&Kh[sr + 64][sc + 8] = ph1b;
        *(uint4*)&Kl[sr + 64][sc]     = pl1a;  *(uint4*)&Kl[sr + 64][sc + 8] = pl1b;
        __syncthreads();

        if (kt < 7) {   // issue next-tile loads; latency drains behind the MFMAs
            size_t off = kb + (size_t)((kt + 1) * 128 + sr) * 64 + sc;
            ph0a = *(const uint4*)(khi + off);       ph0b = *(const uint4*)(khi + off + 8);
            pl0a = *(const uint4*)(klo + off);       pl0b = *(const uint4*)(klo + off + 8);
            size_t off2 = off + 4096;
            ph1a = *(const uint4*)(khi + off2);      ph1b = *(const uint4*)(khi + off2 + 8);
            pl1a = *(const uint4*)(klo + off2);      pl1b = *(const uint4*)(klo + off2 + 8);
        }

        f32x4 acc[4][2];
#pragma unroll
        for (int mi = 0; mi < 4; ++mi) { acc[mi][0] = zero4; acc[mi][1] = zero4; }

#pragma unroll
        for (int ks = 0; ks < 2; ++ks) {
            int kcol = ks * 32 + (lane >> 4) * 8;
            bf16x8 ah[4], al[4];
#pragma unroll
            for (int mi = 0; mi < 4; ++mi) {
                int row = mi * 16 + fr;
                ah[mi] = *(bf16x8*)&Qh[row][kcol];
                al[mi] = *(bf16x8*)&Ql[row][kcol];
            }
#pragma unroll
            for (int ni = 0; ni < 2; ++ni) {
                int krow = wave * 32 + ni * 16 + fr;
                bf16x8 bh8 = *(bf16x8*)&Kh[krow][kcol];
                bf16x8 bl8 = *(bf16x8*)&Kl[krow][kcol];
#pragma unroll
                for (int mi = 0; mi < 4; ++mi) {
                    acc[mi][ni] = MFMA(ah[mi], bh8, acc[mi][ni]);
                    acc[mi][ni] = MFMA(ah[mi], bl8, acc[mi][ni]);
                    acc[mi][ni] = MFMA(al[mi], bh8, acc[mi][ni]);
                }
            }
        }
#pragma unroll
        for (int mi = 0; mi < 4; ++mi)
#pragma unroll
            for (int r = 0; r < 4; ++r)
                rmax[mi][r] = fmaxf(rmax[mi][r], fmaxf(acc[mi][0][r], acc[mi][1][r]));
    }

#pragma unroll
    for (int mi = 0; mi < 4; ++mi)
#pragma unroll
        for (int r = 0; r < 4; ++r) {
            float v = rmax[mi][r];
            v = fmaxf(v, __shfl_xor(v, 1));
            v = fmaxf(v, __shfl_xor(v, 2));
            v = fmaxf(v, __shfl_xor(v, 4));
            v = fmaxf(v, __shfl_xor(v, 8));
            rmax[mi][r] = v;
        }
    if ((lane & 15) == 0) {
        int quad = lane >> 4;
#pragma unroll
        for (int mi = 0; mi < 4; ++mi)
#pragma unroll
            for (int r = 0; r < 4; ++r)
                Mred[mi * 16 + quad * 4 + r][wave] = rmax[mi][r];
    }
    __syncthreads();
    if (tid < 64) {
        float mx = fmaxf(fmaxf(Mred[tid][0], Mred[tid][1]),
                         fmaxf(Mred[tid][2], Mred[tid][3]));
        float dot = 0.f;
#pragma unroll 4
        for (int d = 0; d < 64; ++d)
            dot = fmaf(bf2f(Qh[tid][d]) + bf2f(Ql[tid][d]), km[d], dot);
        Mout[(size_t)bh * L_ + q0 + tid] = mx - dot;
    }
}

// ---------------------------------------------------------------
// top-35 of M[1024] per (b,h)
// ---------------------------------------------------------------
__global__ __launch_bounds__(256) void topk35(
    const float* __restrict__ Min, int* __restrict__ idx_out)
{
    const int bh = blockIdx.x;
    const int tid = threadIdx.x;
    __shared__ float vals[1024];
    __shared__ float wv[4];
    __shared__ int wi[4];
    for (int i = tid; i < 1024; i += 256) vals[i] = Min[(size_t)bh * 1024 + i];
    __syncthreads();
    for (int it = 0; it < U_; ++it) {
        float bv = -INFINITY; int bi = 1 << 30;
        for (int i = tid; i < 1024; i += 256) {
            float x = vals[i];
            if (x > bv) { bv = x; bi = i; }
        }
#pragma unroll
        for (int off = 32; off; off >>= 1) {
            float ov = __shfl_down(bv, off);
            int   oi = __shfl_down(bi, off);
            if (ov > bv || (ov == bv && oi < bi)) { bv = ov; bi = oi; }
        }
        if ((tid & 63) == 0) { wv[tid >> 6] = bv; wi[tid >> 6] = bi; }
        __syncthreads();
        if (tid == 0) {
#pragma unroll
            for (int w = 1; w < 4; ++w) {
                if (wv[w] > bv || (wv[w] == bv && wi[w] < bi)) { bv = wv[w]; bi = wi[w]; }
            }
            idx_out[bh * U_ + it] = bi;
            vals[bi] = -INFINITY;
        }
        __syncthreads();
    }
}

// ---------------------------------------------------------------
// S[u][k] = (q[idx_u] . k_k)/8 masked; grid (128 bh, 8 key-chunks)
// ---------------------------------------------------------------
__global__ __launch_bounds__(256) void scores_red(
    const unsigned short* __restrict__ qhi, const unsigned short* __restrict__ qlo,
    const unsigned short* __restrict__ khi, const unsigned short* __restrict__ klo,
    const int* __restrict__ idx, const int* __restrict__ mask,
    float* __restrict__ S)
{
    __shared__ float Qs[64][36];
    __shared__ float Ks[64][68];
    const int bh = blockIdx.x;
    const int b = bh >> 3;
    const int tid = threadIdx.x;
    const int tk = tid & 63, tg = tid >> 6;

    for (int t = tid; t < 36 * 64; t += 256) {
        int u = t >> 6, d = t & 63;
        float val = 0.f;
        if (u < U_) {
            int l = idx[bh * U_ + u];
            size_t off = ((size_t)bh * L_ + l) * 64 + d;
            val = bf2f(qhi[off]) + bf2f(qlo[off]);
        }
        Qs[d][u] = val;
    }

    const size_t kb = (size_t)bh * L_ * 64;
    const int sr = tid >> 2, sc = (tid & 3) * 16;
    float acc[9];
    const int kt0 = blockIdx.y * 2;
    for (int ki = 0; ki < 2; ++ki) {
        int kt = kt0 + ki;
        if (ki) __syncthreads();
        {
            size_t off = kb + (size_t)(kt * 64 + sr) * 64 + sc;
            uint4 h0 = *(const uint4*)(khi + off);
            uint4 h1 = *(const uint4*)(khi + off + 8);
            uint4 l0 = *(const uint4*)(klo + off);
            uint4 l1 = *(const uint4*)(klo + off + 8);
            unsigned short hv[16], lv[16];
            *(uint4*)hv = h0; *(uint4*)(hv + 8) = h1;
            *(uint4*)lv = l0; *(uint4*)(lv + 8) = l1;
#pragma unroll
            for (int i = 0; i < 16; ++i)
                Ks[sc + i][sr] = bf2f(hv[i]) + bf2f(lv[i]);
        }
        __syncthreads();
#pragma unroll
        for (int j = 0; j < 9; j++) acc[j] = 0.f;
#pragma unroll 4
        for (int d = 0; d < 64; ++d) {
            float kv = Ks[d][tk];
#pragma unroll
            for (int j = 0; j < 9; j++) acc[j] = fmaf(Qs[d][tg + 4 * j], kv, acc[j]);
        }
        const int kcol = kt * 64 + tk;
        const bool msk = (mask[b * L_ + kcol] == 0);
#pragma unroll
        for (int j = 0; j < 9; j++) {
            int u = tg + 4 * j;
            if (u < U_)
                S[((size_t)bh * U_ + u) * 1024 + kcol] = msk ? -INFINITY : acc[j] * 0.125f;
        }
    }
}

// ---------------------------------------------------------------
// softmax over 1024 per row; grid 4480 rows
// ---------------------------------------------------------------
__global__ __launch_bounds__(256) void softmax_rows(float* __restrict__ S)
{
    const size_t base = (size_t)blockIdx.x * 1024;
    const int tid = threadIdx.x;
    __shared__ float redm[4];
    __shared__ float reds[4];
    float4 v = *(const float4*)(S + base + tid * 4);
    float mx = fmaxf(fmaxf(v.x, v.y), fmaxf(v.z, v.w));
#pragma unroll
    for (int off = 32; off; off >>= 1) mx = fmaxf(mx, __shfl_down(mx, off));
    if ((tid & 63) == 0) redm[tid >> 6] = mx;
    __syncthreads();
    mx = fmaxf(fmaxf(redm[0], redm[1]), fmaxf(redm[2], redm[3]));
    float e0 = __expf(v.x - mx), e1 = __expf(v.y - mx);
    float e2 = __expf(v.z - mx), e3 = __expf(v.w - mx);
    float s = e0 + e1 + e2 + e3;
#pragma unroll
    for (int off = 32; off; off >>= 1) s += __shfl_down(s, off);
    if ((tid & 63) == 0) reds[tid >> 6] = s;
    __syncthreads();
    s = reds[0] + reds[1] + reds[2] + reds[3];
    const float inv = 1.0f / s;
    float4 o; o.x = e0 * inv; o.y = e1 * inv; o.z = e2 * inv; o.w = e3 * inv;
    *(float4*)(S + base + tid * 4) = o;
}

// ---------------------------------------------------------------
// ctx partials: grid (128 bh, 8 kc)
// ---------------------------------------------------------------
__global__ __launch_bounds__(256) void ctx_partial(
    const float* __restrict__ S, const float* __restrict__ v,
    float* __restrict__ ctxp)
{
    __shared__ float Vs[128][68];
    __shared__ float Wt[36][128];
    const int bh = blockIdx.x, kc = blockIdx.y;
    const int tid = threadIdx.x;
    const int td = tid & 63, tg = tid >> 6;
    const int lr = tid >> 2, lc0 = (tid & 3) * 16;

    const float* vbase = v + ((size_t)bh * L_ + kc * 128) * 64;
    const float* Sbase = S + (size_t)bh * U_ * 1024 + kc * 128;

#pragma unroll
    for (int hh = 0; hh < 2; ++hh) {
        int row = lr + hh * 64;
        const float* src = vbase + (size_t)row * 64 + lc0;
        *(float4*)&Vs[row][lc0 + 0]  = *(const float4*)(src + 0);
        *(float4*)&Vs[row][lc0 + 4]  = *(const float4*)(src + 4);
        *(float4*)&Vs[row][lc0 + 8]  = *(const float4*)(src + 8);
        *(float4*)&Vs[row][lc0 + 12] = *(const float4*)(src + 12);
    }
    for (int t = tid; t < 36 * 128; t += 256) {
        int u = t >> 7, kk = t & 127;
        Wt[u][kk] = (u < U_) ? Sbase[(size_t)u * 1024 + kk] : 0.f;
    }
    __syncthreads();

    float acc[9];
#pragma unroll
    for (int j = 0; j < 9; j++) acc[j] = 0.f;
#pragma unroll 2
    for (int kk = 0; kk < 128; ++kk) {
        float vv = Vs[kk][td];
#pragma unroll
        for (int j = 0; j < 9; j++) acc[j] = fmaf(Wt[tg + 4 * j][kk], vv, acc[j]);
    }
#pragma unroll
    for (int j = 0; j < 9; j++) {
        int u = tg + 4 * j;
        if (u < U_)
            ctxp[((size_t)(kc * 128 + bh) * 36 + u) * 64 + td] = acc[j];
    }
}

// ---------------------------------------------------------------
// ctxd[bh][u][d] = sum_kc ctxp - vmean[bh][d] ; grid 1120 x 256
// ---------------------------------------------------------------
__global__ __launch_bounds__(256) void ctx_reduce_diff(
    const float* __restrict__ ctxp, const float* __restrict__ vmean,
    float* __restrict__ ctxd)
{
    const int i = blockIdx.x * 256 + threadIdx.x;   // 128*35*64 = 286720
    const int d = i & 63;
    const int rest = i >> 6;
    const int u = rest % U_;
    const int bh = rest / U_;
    float s = 0.f;
#pragma unroll
    for (int kc = 0; kc < 8; ++kc)
        s += ctxp[((size_t)(kc * 128 + bh) * 36 + u) * 64 + d];
    ctxd[i] = s - vmean[(size_t)bh * 64 + d];
}

// ---------------------------------------------------------------
// obase[b][n] = dot(xbar[b], Wo[n]) + bo[n] ; grid 128 (16 b x 8 nchunk)
// ---------------------------------------------------------------
__global__ __launch_bounds__(256) void vmean_proj(
    const float* __restrict__ vmean, const float* __restrict__ Wo,
    const float* __restrict__ bo, float* __restrict__ obase)
{
    const int b = blockIdx.x >> 3, n0 = (blockIdx.x & 7) * 64;
    const int tid = threadIdx.x;
    __shared__ float xbar[512];
    __shared__ float psum[64][5];
    for (int i = tid; i < 512; i += 256)
        xbar[i] = vmean[(size_t)(b * 8 + (i >> 6)) * 64 + (i & 63)];
    __syncthreads();
    const int n = n0 + (tid >> 2), fq = (tid & 3) * 128;
    float s = 0.f;
    for (int f = 0; f < 128; f += 4) {
        float4 w = *(const float4*)(Wo + (size_t)n * 512 + fq + f);
        s += xbar[fq + f] * w.x + xbar[fq + f + 1] * w.y +
             xbar[fq + f + 2] * w.z + xbar[fq + f + 3] * w.w;
    }
    psum[tid >> 2][tid & 3] = s;
    __syncthreads();
    if (tid < 64)
        obase[(size_t)b * 512 + n0 + tid] =
            psum[tid][0] + psum[tid][1] + psum[tid][2] + psum[tid][3] + bo[n0 + tid];
}

// ---------------------------------------------------------------
// out[b][l][:] = obase[b][:] ; grid 8192 x 256 (float4)
// ---------------------------------------------------------------
__global__ void broadcast_out(const float* __restrict__ obase, float* __restrict__ out)
{
    const size_t e = ((size_t)blockIdx.x * 256 + threadIdx.x) * 4;
    const int n = (int)(e & 511);
    const int b = (int)(e >> 19);
    *(float4*)(out + e) = *(const float4*)(obase + (b << 9) + n);
}

// ---------------------------------------------------------------
// out[b][l_u][n] += ctxd[bh][u] . Wo[n][h*64..]; grid 128 bh x 256
// all 35 ctxd rows staged in LDS; u tiled 5x7 to keep VGPRs low
// ---------------------------------------------------------------
__global__ __launch_bounds__(256) void delta_out(
    const float* __restrict__ ctxd, const int* __restrict__ idx,
    const float* __restrict__ Wo, float* __restrict__ out)
{
    const int bh = blockIdx.x, b = bh >> 3, h = bh & 7;
    const int tid = threadIdx.x;
    __shared__ float sd[U_][64];
    __shared__ int ls[U_];
    if (tid < U_) ls[tid] = idx[bh * U_ + tid];
    for (int t = tid; t < U_ * 64; t += 256)
        sd[t >> 6][t & 63] = ctxd[(size_t)bh * U_ * 64 + t];
    __syncthreads();

    const float* w0p = Wo + (size_t)tid * 512 + h * 64;
    const float* w1p = w0p + (size_t)256 * 512;
    for (int ut = 0; ut < 5; ++ut) {
        float a0[7], a1[7];
#pragma unroll
        for (int k = 0; k < 7; ++k) { a0[k] = 0.f; a1[k] = 0.f; }
        for (int jc = 0; jc < 16; ++jc) {
            float4 w0 = *(const float4*)(w0p + jc * 4);
            float4 w1 = *(const float4*)(w1p + jc * 4);
#pragma unroll
            for (int k = 0; k < 7; ++k) {
                float4 dv = *(const float4*)&sd[ut * 7 + k][jc * 4];
                a0[k] = fmaf(dv.w, w0.w, fmaf(dv.z, w0.z, fmaf(dv.y, w0.y, fmaf(dv.x, w0.x, a0[k]))));
                a1[k] = fmaf(dv.w, w1.w, fmaf(dv.z, w1.z, fmaf(dv.y, w1.y, fmaf(dv.x, w1.x, a1[k]))));
            }
        }
#pragma unroll
        for (int k = 0; k < 7; ++k) {
            int u = ut * 7 + k;
            float* orow = out + ((size_t)b * L_ + ls[u]) * 512;
            atomicAdd(orow + tid, a0[k]);
            atomicAdd(orow + tid + 256, a1[k]);
        }
    }
}

// ---------------------------------------------------------------
extern "C" void kernel_launch(void* const* d_in, const int* in_sizes, int n_in,
                              void* d_out, int out_size, void* d_ws, size_t ws_size,
                              hipStream_t stream)
{
    (void)in_sizes; (void)n_in; (void)out_size; (void)ws_size;
    const float* query = (const float*)d_in[0];
    const float* key   = (const float*)d_in[1];
    const float* value = (const float*)d_in[2];
    const int*   mask  = (const int*)d_in[3];
    const float* Wq = (const float*)d_in[4];
    const float* bq = (const float*)d_in[5];
    const float* Wk = (const float*)d_in[6];
    const float* bk = (const float*)d_in[7];
    const float* Wv = (const float*)d_in[8];
    const float* bvp = (const float*)d_in[9];
    const float* Wo = (const float*)d_in[10];
    const float* bo = (const float*)d_in[11];
    float* out = (float*)d_out;

    float* ws = (float*)d_ws;
    float* v      = ws + OFF_V;
    unsigned short* q_hi = (unsigned short*)(ws + OFF_QHI);
    unsigned short* q_lo = (unsigned short*)(ws + OFF_QLO);
    unsigned short* k_hi = (unsigned short*)(ws + OFF_KHI);
    unsigned short* k_lo = (unsigned short*)(ws + OFF_KLO);
    float* ctxp   = ws + OFF_CTXP;
    float* S      = ws + OFF_S;
    float* Marr   = ws + OFF_M;
    float* kmean  = ws + OFF_KMEAN;
    float* vmean  = ws + OFF_VMEAN;
    float* ctxd   = ws + OFF_CTXD;
    int*   idx    = (int*)(ws + OFF_IDX);
    float* obase  = ws + OFF_OBASE;
    unsigned short* wqh = (unsigned short*)(ws + OFF_WQH);
    unsigned short* wql = (unsigned short*)(ws + OFF_WQL);
    unsigned short* wkh = (unsigned short*)(ws + OFF_WKH);
    unsigned short* wkl = (unsigned short*)(ws + OFF_WKL);
    unsigned short* wvh = (unsigned short*)(ws + OFF_WVH);
    unsigned short* wvl = (unsigned short*)(ws + OFF_WVL);

    // weight splits (fused)
    split_w3<<<3072, 256, 0, stream>>>(Wq, Wk, Wv, wqh, wql, wkh, wkl, wvh, wvl);

    // projections (bf16x2 MFMA); q,k emit hi/lo bf16, v emits fp32
    const dim3 ggemm(128, 4);
    gemm_mfma<<<ggemm, 256, 0, stream>>>(query, wqh, wql, bq, nullptr, q_hi, q_lo, 1);
    gemm_mfma<<<ggemm, 256, 0, stream>>>(key,   wkh, wkl, bk, nullptr, k_hi, k_lo, 1);
    gemm_mfma<<<ggemm, 256, 0, stream>>>(value, wvh, wvl, bvp, v, nullptr, nullptr, 1);

    // per-(b,h) means (fused) + base output row
    means_fused<<<256, 256, 0, stream>>>(k_hi, k_lo, v, kmean, vmean);
    vmean_proj<<<128, 256, 0, stream>>>(vmean, Wo, bo, obase);

    // sparsity measure M (MFMA, XCD-swizzled grid) and top-35
    qk_rowmax_mfma<<<dim3(128, 16), 256, 0, stream>>>(q_hi, q_lo, k_hi, k_lo, kmean, Marr);
    topk35<<<128, 256, 0, stream>>>(Marr, idx);

    // reduced attention (K-split for parallelism)
    scores_red<<<dim3(128, 8), 256, 0, stream>>>(q_hi, q_lo, k_hi, k_lo, idx, mask, S);
    softmax_rows<<<B_ * H_ * U_, 256, 0, stream>>>(S);
    ctx_partial<<<dim3(128, 8), 256, 0, stream>>>(S, v, ctxp);   // ctxp aliases q_hi (dead)
    ctx_reduce_diff<<<1120, 256, 0, stream>>>(ctxp, vmean, ctxd);

    // output = broadcast base row + sparse delta (replaces full Wo GEMM)
    broadcast_out<<<8192, 256, 0, stream>>>(obase, out);
    delta_out<<<128, 256, 0, stream>>>(ctxd, idx, Wo, out);
}

// Round 7
// 476.578 us; speedup vs baseline: 1.1133x; 1.1133x over previous
//
#include <hip/hip_runtime.h>
#include <math.h>

#define B_ 16
#define L_ 1024
#define H_ 8
#define U_ 35

typedef float f32x4 __attribute__((ext_vector_type(4)));
typedef short bf16x8 __attribute__((ext_vector_type(8)));

__device__ __forceinline__ unsigned short f2bf(float x) {
    unsigned int u = __float_as_uint(x);
    u += 0x7FFFu + ((u >> 16) & 1u);      // round-to-nearest-even
    return (unsigned short)(u >> 16);
}
__device__ __forceinline__ float bf2f(unsigned short b) {
    return __uint_as_float(((unsigned int)b) << 16);
}

#define MFMA(a, b, c) __builtin_amdgcn_mfma_f32_16x16x32_bf16((a), (b), (c), 0, 0, 0)

// ---------------- workspace layout (float-element offsets) ----------------
#define OFF_V      ((size_t)0)           // 8388608 f
#define OFF_QHI    ((size_t)8388608)     // 4194304
#define OFF_QLO    ((size_t)12582912)    // 4194304
#define OFF_CTXP   OFF_QHI               // ctx partials alias q_hi (dead after scores)
#define OFF_KHI    ((size_t)16777216)    // 4194304
#define OFF_KLO    ((size_t)20971520)    // 4194304
#define OFF_S      ((size_t)25165824)    // 4587520
#define OFF_WQH    OFF_S                 // W splits alias S (dead before scores)
#define OFF_WQL    ((size_t)(OFF_S + 131072))
#define OFF_WKH    ((size_t)(OFF_S + 262144))
#define OFF_WKL    ((size_t)(OFF_S + 393216))
#define OFF_WVH    ((size_t)(OFF_S + 524288))
#define OFF_WVL    ((size_t)(OFF_S + 655360))
#define OFF_M      ((size_t)29753344)    // 131072
#define OFF_KMEAN  ((size_t)29884416)    // 8192
#define OFF_VMEAN  ((size_t)29892608)    // 8192
#define OFF_CTXD   ((size_t)29900800)    // 286720 (ctx - vmean diffs)
#define OFF_IDX    ((size_t)30187520)    // 4480
#define OFF_OBASE  ((size_t)30192000)    // 8192 (per-b base output row)
// end ~30.2M f = ~121 MB

// ---------------------------------------------------------------
// split Wq/Wk/Wv fp32 -> hi/lo bf16; grid 3072 x 256
// ---------------------------------------------------------------
__global__ __launch_bounds__(256) void split_w3(
    const float* __restrict__ Wq, const float* __restrict__ Wk,
    const float* __restrict__ Wv,
    unsigned short* __restrict__ wqh, unsigned short* __restrict__ wql,
    unsigned short* __restrict__ wkh, unsigned short* __restrict__ wkl,
    unsigned short* __restrict__ wvh, unsigned short* __restrict__ wvl)
{
    const int w = blockIdx.x >> 10;
    const int i = (blockIdx.x & 1023) * 256 + threadIdx.x;
    const float* W = (w == 0) ? Wq : (w == 1) ? Wk : Wv;
    unsigned short* hi = (w == 0) ? wqh : (w == 1) ? wkh : wvh;
    unsigned short* lo = (w == 0) ? wql : (w == 1) ? wkl : wvl;
    float x = W[i];
    unsigned short h = f2bf(x);
    hi[i] = h;
    lo[i] = f2bf(x - bf2f(h));
}

// ---------------------------------------------------------------
// bf16x2 MFMA GEMM: C[m,n] = sum_k A[m,k]*W[n,k] + bias[n]
// ---------------------------------------------------------------
__global__ __launch_bounds__(256) void gemm_mfma(
    const float* __restrict__ A,
    const unsigned short* __restrict__ Whi, const unsigned short* __restrict__ Wlo,
    const float* __restrict__ bias,
    float* __restrict__ outf,
    unsigned short* __restrict__ ohi, unsigned short* __restrict__ olo,
    const int head_layout)
{
    __shared__ unsigned short Ah[128][40];
    __shared__ unsigned short Al[128][40];
    __shared__ unsigned short Bh[128][40];
    __shared__ unsigned short Bl[128][40];
    const int tid = threadIdx.x, lane = tid & 63, wave = tid >> 6;
    const int m0 = blockIdx.x * 128, n0 = blockIdx.y * 128;
    const int wm = (wave >> 1) * 64, wn = (wave & 1) * 64;

    f32x4 zero4 = {0.f, 0.f, 0.f, 0.f};
    f32x4 acc[4][4];
#pragma unroll
    for (int i = 0; i < 4; i++)
#pragma unroll
        for (int j = 0; j < 4; j++) acc[i][j] = zero4;

    const int ar = tid >> 3, ac = (tid & 7) * 4;
    const int br = tid >> 2, bc = (tid & 3) * 8;
    const int kc = (lane >> 4) * 8;
    const int fr = lane & 15;

    for (int k0 = 0; k0 < 512; k0 += 32) {
        if (k0) __syncthreads();
#pragma unroll
        for (int p = 0; p < 4; ++p) {
            float4 a4 = *(const float4*)(A + (size_t)(m0 + ar + p * 32) * 512 + k0 + ac);
            ushort4 h4, l4;
            h4.x = f2bf(a4.x); l4.x = f2bf(a4.x - bf2f(h4.x));
            h4.y = f2bf(a4.y); l4.y = f2bf(a4.y - bf2f(h4.y));
            h4.z = f2bf(a4.z); l4.z = f2bf(a4.z - bf2f(h4.z));
            h4.w = f2bf(a4.w); l4.w = f2bf(a4.w - bf2f(h4.w));
            *(ushort4*)&Ah[ar + p * 32][ac] = h4;
            *(ushort4*)&Al[ar + p * 32][ac] = l4;
        }
#pragma unroll
        for (int p = 0; p < 2; ++p) {
            size_t off = (size_t)(n0 + br + p * 64) * 512 + k0 + bc;
            *(uint4*)&Bh[br + p * 64][bc] = *(const uint4*)(Whi + off);
            *(uint4*)&Bl[br + p * 64][bc] = *(const uint4*)(Wlo + off);
        }
        __syncthreads();

        bf16x8 ah[4], al[4];
#pragma unroll
        for (int mi = 0; mi < 4; ++mi) {
            int row = wm + mi * 16 + fr;
            ah[mi] = *(bf16x8*)&Ah[row][kc];
            al[mi] = *(bf16x8*)&Al[row][kc];
        }
#pragma unroll
        for (int ni = 0; ni < 4; ++ni) {
            int rn = wn + ni * 16 + fr;
            bf16x8 bh8 = *(bf16x8*)&Bh[rn][kc];
            bf16x8 bl8 = *(bf16x8*)&Bl[rn][kc];
#pragma unroll
            for (int mi = 0; mi < 4; ++mi) {
                acc[mi][ni] = MFMA(ah[mi], bh8, acc[mi][ni]);
                acc[mi][ni] = MFMA(ah[mi], bl8, acc[mi][ni]);
                acc[mi][ni] = MFMA(al[mi], bh8, acc[mi][ni]);
            }
        }
    }

    const int col = lane & 15, rq = (lane >> 4) * 4;
#pragma unroll
    for (int ni = 0; ni < 4; ++ni) {
        int n = n0 + wn + ni * 16 + col;
        float bn = bias[n];
#pragma unroll
        for (int mi = 0; mi < 4; ++mi) {
#pragma unroll
            for (int r = 0; r < 4; ++r) {
                int m = m0 + wm + mi * 16 + rq + r;
                float val = acc[mi][ni][r] + bn;
                if (head_layout) {
                    size_t off = ((size_t)((m >> 10) * H_ + (n >> 6)) * L_ + (m & 1023)) * 64 + (n & 63);
                    if (outf) outf[off] = val;
                    if (ohi) {
                        unsigned short h = f2bf(val);
                        ohi[off] = h;
                        olo[off] = f2bf(val - bf2f(h));
                    }
                } else {
                    outf[(size_t)m * 512 + n] = val;
                }
            }
        }
    }
}

// ---------------------------------------------------------------
// fused means: blocks 0..127 -> kmean (from k hi/lo), 128..255 -> vmean (fp32)
// ---------------------------------------------------------------
__global__ __launch_bounds__(256) void means_fused(
    const unsigned short* __restrict__ khi, const unsigned short* __restrict__ klo,
    const float* __restrict__ v, float* __restrict__ kmean, float* __restrict__ vmean)
{
    const int which = blockIdx.x >> 7;
    const int bh = blockIdx.x & 127;
    const int d = threadIdx.x & 63, g = threadIdx.x >> 6;
    __shared__ float red[4][64];
    float s = 0.f;
    if (which == 0) {
        size_t base = ((size_t)bh * L_ + g * 256) * 64 + d;
#pragma unroll 8
        for (int l = 0; l < 256; l++) {
            size_t o = base + (size_t)l * 64;
            s += bf2f(khi[o]) + bf2f(klo[o]);
        }
    } else {
        const float* p = v + ((size_t)bh * L_ + g * 256) * 64 + d;
#pragma unroll 8
        for (int l = 0; l < 256; l++) s += p[(size_t)l * 64];
    }
    red[g][d] = s;
    __syncthreads();
    if (threadIdx.x < 64) {
        const int dd = threadIdx.x;
        float m = (red[0][dd] + red[1][dd] + red[2][dd] + red[3][dd]) * (1.0f / 1024.0f);
        (which == 0 ? kmean : vmean)[(size_t)bh * 64 + dd] = m;
    }
}

// ---------------------------------------------------------------
// M[l] = max_k(q_l . k_k) - q_l . kmean via bf16x2 MFMA, reg-prefetch staging
// grid (128 bh, 16 qt): linid = bh + 128*qt -> xcd = bh%8, so all 16
// q-tiles of a bh land on one XCD and share its K tiles in that L2.
// ---------------------------------------------------------------
__global__ __launch_bounds__(256) void qk_rowmax_mfma(
    const unsigned short* __restrict__ qhi, const unsigned short* __restrict__ qlo,
    const unsigned short* __restrict__ khi, const unsigned short* __restrict__ klo,
    const float* __restrict__ kmean, float* __restrict__ Mout)
{
    __shared__ unsigned short Qh[64][72], Ql[64][72];
    __shared__ unsigned short Kh[128][72], Kl[128][72];
    __shared__ float Mred[64][4];
    __shared__ float km[64];
    const int bh = blockIdx.x, q0 = blockIdx.y * 64;
    const int tid = threadIdx.x, lane = tid & 63, wave = tid >> 6;

    if (tid < 64) km[tid] = kmean[bh * 64 + tid];
    {
        int r = tid >> 2, c = (tid & 3) * 16;
        size_t off = ((size_t)bh * L_ + q0 + r) * 64 + c;
        *(uint4*)&Qh[r][c]     = *(const uint4*)(qhi + off);
        *(uint4*)&Qh[r][c + 8] = *(const uint4*)(qhi + off + 8);
        *(uint4*)&Ql[r][c]     = *(const uint4*)(qlo + off);
        *(uint4*)&Ql[r][c + 8] = *(const uint4*)(qlo + off + 8);
    }

    float rmax[4][4];
#pragma unroll
    for (int mi = 0; mi < 4; ++mi)
#pragma unroll
        for (int r = 0; r < 4; ++r) rmax[mi][r] = -INFINITY;

    const size_t kb = (size_t)bh * L_ * 64;
    const int sr = tid >> 2, sc = (tid & 3) * 16;
    const int fr = lane & 15;
    f32x4 zero4 = {0.f, 0.f, 0.f, 0.f};

    // register prefetch of tile 0
    uint4 ph0a, ph0b, pl0a, pl0b, ph1a, ph1b, pl1a, pl1b;
    {
        size_t off = kb + (size_t)sr * 64 + sc;
        ph0a = *(const uint4*)(khi + off);       ph0b = *(const uint4*)(khi + off + 8);
        pl0a = *(const uint4*)(klo + off);       pl0b = *(const uint4*)(klo + off + 8);
        size_t off2 = off + 4096;
        ph1a = *(const uint4*)(khi + off2);      ph1b = *(const uint4*)(khi + off2 + 8);
        pl1a = *(const uint4*)(klo + off2);      pl1b = *(const uint4*)(klo + off2 + 8);
    }

    for (int kt = 0; kt < 8; ++kt) {
        __syncthreads();   // previous tile's readers done (also fences Q/km stage)
        *(uint4*)&Kh[sr][sc]          = ph0a;  *(uint4*)&Kh[sr][sc + 8]      = ph0b;
        *(uint4*)&Kl[sr][sc]          = pl0a;  *(uint4*)&Kl[sr][sc + 8]      = pl0b;
        *(uint4*)&Kh[sr + 64][sc]     = ph1a;  *(uint4*)&Kh[sr + 64][sc + 8] = ph1b;
        *(uint4*)&Kl[sr + 64][sc]     = pl1a;  *(uint4*)&Kl[sr + 64][sc + 8] = pl1b;
        __syncthreads();

        if (kt < 7) {   // issue next-tile loads; latency drains behind the MFMAs
            size_t off = kb + (size_t)((kt + 1) * 128 + sr) * 64 + sc;
            ph0a = *(const uint4*)(khi + off);       ph0b = *(const uint4*)(khi + off + 8);
            pl0a = *(const uint4*)(klo + off);       pl0b = *(const uint4*)(klo + off + 8);
            size_t off2 = off + 4096;
            ph1a = *(const uint4*)(khi + off2);      ph1b = *(const uint4*)(khi + off2 + 8);
            pl1a = *(const uint4*)(klo + off2);      pl1b = *(const uint4*)(klo + off2 + 8);
        }

        f32x4 acc[4][2];
#pragma unroll
        for (int mi = 0; mi < 4; ++mi) { acc[mi][0] = zero4; acc[mi][1] = zero4; }

#pragma unroll
        for (int ks = 0; ks < 2; ++ks) {
            int kcol = ks * 32 + (lane >> 4) * 8;
            bf16x8 ah[4], al[4];
#pragma unroll
            for (int mi = 0; mi < 4; ++mi) {
                int row = mi * 16 + fr;
                ah[mi] = *(bf16x8*)&Qh[row][kcol];
                al[mi] = *(bf16x8*)&Ql[row][kcol];
            }
#pragma unroll
            for (int ni = 0; ni < 2; ++ni) {
                int krow = wave * 32 + ni * 16 + fr;
                bf16x8 bh8 = *(bf16x8*)&Kh[krow][kcol];
                bf16x8 bl8 = *(bf16x8*)&Kl[krow][kcol];
#pragma unroll
                for (int mi = 0; mi < 4; ++mi) {
                    acc[mi][ni] = MFMA(ah[mi], bh8, acc[mi][ni]);
                    acc[mi][ni] = MFMA(ah[mi], bl8, acc[mi][ni]);
                    acc[mi][ni] = MFMA(al[mi], bh8, acc[mi][ni]);
                }
            }
        }
#pragma unroll
        for (int mi = 0; mi < 4; ++mi)
#pragma unroll
            for (int r = 0; r < 4; ++r)
                rmax[mi][r] = fmaxf(rmax[mi][r], fmaxf(acc[mi][0][r], acc[mi][1][r]));
    }

#pragma unroll
    for (int mi = 0; mi < 4; ++mi)
#pragma unroll
        for (int r = 0; r < 4; ++r) {
            float v = rmax[mi][r];
            v = fmaxf(v, __shfl_xor(v, 1));
            v = fmaxf(v, __shfl_xor(v, 2));
            v = fmaxf(v, __shfl_xor(v, 4));
            v = fmaxf(v, __shfl_xor(v, 8));
            rmax[mi][r] = v;
        }
    if ((lane & 15) == 0) {
        int quad = lane >> 4;
#pragma unroll
        for (int mi = 0; mi < 4; ++mi)
#pragma unroll
            for (int r = 0; r < 4; ++r)
                Mred[mi * 16 + quad * 4 + r][wave] = rmax[mi][r];
    }
    __syncthreads();
    if (tid < 64) {
        float mx = fmaxf(fmaxf(Mred[tid][0], Mred[tid][1]),
                         fmaxf(Mred[tid][2], Mred[tid][3]));
        float dot = 0.f;
#pragma unroll 4
        for (int d = 0; d < 64; ++d)
            dot = fmaf(bf2f(Qh[tid][d]) + bf2f(Ql[tid][d]), km[d], dot);
        Mout[(size_t)bh * L_ + q0 + tid] = mx - dot;
    }
}

// ---------------------------------------------------------------
// top-35 of M[1024] per (b,h)
// ---------------------------------------------------------------
__global__ __launch_bounds__(256) void topk35(
    const float* __restrict__ Min, int* __restrict__ idx_out)
{
    const int bh = blockIdx.x;
    const int tid = threadIdx.x;
    __shared__ float vals[1024];
    __shared__ float wv[4];
    __shared__ int wi[4];
    for (int i = tid; i < 1024; i += 256) vals[i] = Min[(size_t)bh * 1024 + i];
    __syncthreads();
    for (int it = 0; it < U_; ++it) {
        float bv = -INFINITY; int bi = 1 << 30;
        for (int i = tid; i < 1024; i += 256) {
            float x = vals[i];
            if (x > bv) { bv = x; bi = i; }
        }
#pragma unroll
        for (int off = 32; off; off >>= 1) {
            float ov = __shfl_down(bv, off);
            int   oi = __shfl_down(bi, off);
            if (ov > bv || (ov == bv && oi < bi)) { bv = ov; bi = oi; }
        }
        if ((tid & 63) == 0) { wv[tid >> 6] = bv; wi[tid >> 6] = bi; }
        __syncthreads();
        if (tid == 0) {
#pragma unroll
            for (int w = 1; w < 4; ++w) {
                if (wv[w] > bv || (wv[w] == bv && wi[w] < bi)) { bv = wv[w]; bi = wi[w]; }
            }
            idx_out[bh * U_ + it] = bi;
            vals[bi] = -INFINITY;
        }
        __syncthreads();
    }
}

// ---------------------------------------------------------------
// S[u][k] = (q[idx_u] . k_k)/8 masked; grid (128 bh, 8 key-chunks)
// ---------------------------------------------------------------
__global__ __launch_bounds__(256) void scores_red(
    const unsigned short* __restrict__ qhi, const unsigned short* __restrict__ qlo,
    const unsigned short* __restrict__ khi, const unsigned short* __restrict__ klo,
    const int* __restrict__ idx, const int* __restrict__ mask,
    float* __restrict__ S)
{
    __shared__ float Qs[64][36];
    __shared__ float Ks[64][68];
    const int bh = blockIdx.x;
    const int b = bh >> 3;
    const int tid = threadIdx.x;
    const int tk = tid & 63, tg = tid >> 6;

    for (int t = tid; t < 36 * 64; t += 256) {
        int u = t >> 6, d = t & 63;
        float val = 0.f;
        if (u < U_) {
            int l = idx[bh * U_ + u];
            size_t off = ((size_t)bh * L_ + l) * 64 + d;
            val = bf2f(qhi[off]) + bf2f(qlo[off]);
        }
        Qs[d][u] = val;
    }

    const size_t kb = (size_t)bh * L_ * 64;
    const int sr = tid >> 2, sc = (tid & 3) * 16;
    float acc[9];
    const int kt0 = blockIdx.y * 2;
    for (int ki = 0; ki < 2; ++ki) {
        int kt = kt0 + ki;
        if (ki) __syncthreads();
        {
            size_t off = kb + (size_t)(kt * 64 + sr) * 64 + sc;
            uint4 h0 = *(const uint4*)(khi + off);
            uint4 h1 = *(const uint4*)(khi + off + 8);
            uint4 l0 = *(const uint4*)(klo + off);
            uint4 l1 = *(const uint4*)(klo + off + 8);
            unsigned short hv[16], lv[16];
            *(uint4*)hv = h0; *(uint4*)(hv + 8) = h1;
            *(uint4*)lv = l0; *(uint4*)(lv + 8) = l1;
#pragma unroll
            for (int i = 0; i < 16; ++i)
                Ks[sc + i][sr] = bf2f(hv[i]) + bf2f(lv[i]);
        }
        __syncthreads();
#pragma unroll
        for (int j = 0; j < 9; j++) acc[j] = 0.f;
#pragma unroll 4
        for (int d = 0; d < 64; ++d) {
            float kv = Ks[d][tk];
#pragma unroll
            for (int j = 0; j < 9; j++) acc[j] = fmaf(Qs[d][tg + 4 * j], kv, acc[j]);
        }
        const int kcol = kt * 64 + tk;
        const bool msk = (mask[b * L_ + kcol] == 0);
#pragma unroll
        for (int j = 0; j < 9; j++) {
            int u = tg + 4 * j;
            if (u < U_)
                S[((size_t)bh * U_ + u) * 1024 + kcol] = msk ? -INFINITY : acc[j] * 0.125f;
        }
    }
}

// ---------------------------------------------------------------
// softmax over 1024 per row; grid 4480 rows
// ---------------------------------------------------------------
__global__ __launch_bounds__(256) void softmax_rows(float* __restrict__ S)
{
    const size_t base = (size_t)blockIdx.x * 1024;
    const int tid = threadIdx.x;
    __shared__ float redm[4];
    __shared__ float reds[4];
    float4 v = *(const float4*)(S + base + tid * 4);
    float mx = fmaxf(fmaxf(v.x, v.y), fmaxf(v.z, v.w));
#pragma unroll
    for (int off = 32; off; off >>= 1) mx = fmaxf(mx, __shfl_down(mx, off));
    if ((tid & 63) == 0) redm[tid >> 6] = mx;
    __syncthreads();
    mx = fmaxf(fmaxf(redm[0], redm[1]), fmaxf(redm[2], redm[3]));
    float e0 = __expf(v.x - mx), e1 = __expf(v.y - mx);
    float e2 = __expf(v.z - mx), e3 = __expf(v.w - mx);
    float s = e0 + e1 + e2 + e3;
#pragma unroll
    for (int off = 32; off; off >>= 1) s += __shfl_down(s, off);
    if ((tid & 63) == 0) reds[tid >> 6] = s;
    __syncthreads();
    s = reds[0] + reds[1] + reds[2] + reds[3];
    const float inv = 1.0f / s;
    float4 o; o.x = e0 * inv; o.y = e1 * inv; o.z = e2 * inv; o.w = e3 * inv;
    *(float4*)(S + base + tid * 4) = o;
}

// ---------------------------------------------------------------
// ctx partials: grid (128 bh, 8 kc)
// ---------------------------------------------------------------
__global__ __launch_bounds__(256) void ctx_partial(
    const float* __restrict__ S, const float* __restrict__ v,
    float* __restrict__ ctxp)
{
    __shared__ float Vs[128][68];
    __shared__ float Wt[36][128];
    const int bh = blockIdx.x, kc = blockIdx.y;
    const int tid = threadIdx.x;
    const int td = tid & 63, tg = tid >> 6;
    const int lr = tid >> 2, lc0 = (tid & 3) * 16;

    const float* vbase = v + ((size_t)bh * L_ + kc * 128) * 64;
    const float* Sbase = S + (size_t)bh * U_ * 1024 + kc * 128;

#pragma unroll
    for (int hh = 0; hh < 2; ++hh) {
        int row = lr + hh * 64;
        const float* src = vbase + (size_t)row * 64 + lc0;
        *(float4*)&Vs[row][lc0 + 0]  = *(const float4*)(src + 0);
        *(float4*)&Vs[row][lc0 + 4]  = *(const float4*)(src + 4);
        *(float4*)&Vs[row][lc0 + 8]  = *(const float4*)(src + 8);
        *(float4*)&Vs[row][lc0 + 12] = *(const float4*)(src + 12);
    }
    for (int t = tid; t < 36 * 128; t += 256) {
        int u = t >> 7, kk = t & 127;
        Wt[u][kk] = (u < U_) ? Sbase[(size_t)u * 1024 + kk] : 0.f;
    }
    __syncthreads();

    float acc[9];
#pragma unroll
    for (int j = 0; j < 9; j++) acc[j] = 0.f;
#pragma unroll 2
    for (int kk = 0; kk < 128; ++kk) {
        float vv = Vs[kk][td];
#pragma unroll
        for (int j = 0; j < 9; j++) acc[j] = fmaf(Wt[tg + 4 * j][kk], vv, acc[j]);
    }
#pragma unroll
    for (int j = 0; j < 9; j++) {
        int u = tg + 4 * j;
        if (u < U_)
            ctxp[((size_t)(kc * 128 + bh) * 36 + u) * 64 + td] = acc[j];
    }
}

// ---------------------------------------------------------------
// ctxd[bh][u][d] = sum_kc ctxp - vmean[bh][d] ; grid 1120 x 256
// ---------------------------------------------------------------
__global__ __launch_bounds__(256) void ctx_reduce_diff(
    const float* __restrict__ ctxp, const float* __restrict__ vmean,
    float* __restrict__ ctxd)
{
    const int i = blockIdx.x * 256 + threadIdx.x;   // 128*35*64 = 286720
    const int d = i & 63;
    const int rest = i >> 6;
    const int u = rest % U_;
    const int bh = rest / U_;
    float s = 0.f;
#pragma unroll
    for (int kc = 0; kc < 8; ++kc)
        s += ctxp[((size_t)(kc * 128 + bh) * 36 + u) * 64 + d];
    ctxd[i] = s - vmean[(size_t)bh * 64 + d];
}

// ---------------------------------------------------------------
// obase[b][n] = dot(xbar[b], Wo[n]) + bo[n] ; grid 128 (16 b x 8 nchunk)
// ---------------------------------------------------------------
__global__ __launch_bounds__(256) void vmean_proj(
    const float* __restrict__ vmean, const float* __restrict__ Wo,
    const float* __restrict__ bo, float* __restrict__ obase)
{
    const int b = blockIdx.x >> 3, n0 = (blockIdx.x & 7) * 64;
    const int tid = threadIdx.x;
    __shared__ float xbar[512];
    __shared__ float psum[64][5];
    for (int i = tid; i < 512; i += 256)
        xbar[i] = vmean[(size_t)(b * 8 + (i >> 6)) * 64 + (i & 63)];
    __syncthreads();
    const int n = n0 + (tid >> 2), fq = (tid & 3) * 128;
    float s = 0.f;
    for (int f = 0; f < 128; f += 4) {
        float4 w = *(const float4*)(Wo + (size_t)n * 512 + fq + f);
        s += xbar[fq + f] * w.x + xbar[fq + f + 1] * w.y +
             xbar[fq + f + 2] * w.z + xbar[fq + f + 3] * w.w;
    }
    psum[tid >> 2][tid & 3] = s;
    __syncthreads();
    if (tid < 64)
        obase[(size_t)b * 512 + n0 + tid] =
            psum[tid][0] + psum[tid][1] + psum[tid][2] + psum[tid][3] + bo[n0 + tid];
}

// ---------------------------------------------------------------
// out[b][l][:] = obase[b][:] ; grid 8192 x 256 (float4)
// ---------------------------------------------------------------
__global__ void broadcast_out(const float* __restrict__ obase, float* __restrict__ out)
{
    const size_t e = ((size_t)blockIdx.x * 256 + threadIdx.x) * 4;
    const int n = (int)(e & 511);
    const int b = (int)(e >> 19);
    *(float4*)(out + e) = *(const float4*)(obase + (b << 9) + n);
}

// ---------------------------------------------------------------
// out[b][l_u][n] += ctxd[bh][u] . Wo[n][h*64..]
// grid (128 bh, 4 col-chunks) x 128 threads; one column n per thread.
// Wo slice in 16 float4 VGPRs (read once); ctxd rows in LDS (broadcast
// reads, conflict-free); coalesced per-wave atomics.
// ---------------------------------------------------------------
__global__ __launch_bounds__(128) void delta_out(
    const float* __restrict__ ctxd, const int* __restrict__ idx,
    const float* __restrict__ Wo, float* __restrict__ out)
{
    const int bh = blockIdx.x, b = bh >> 3, h = bh & 7;
    const int tid = threadIdx.x;
    const int n = blockIdx.y * 128 + tid;
    __shared__ float sd[U_][64];
    __shared__ int ls[U_];
    if (tid < U_) ls[tid] = idx[bh * U_ + tid];
    for (int t = tid; t < U_ * 64; t += 128)
        sd[t >> 6][t & 63] = ctxd[(size_t)bh * U_ * 64 + t];

    float4 w[16];
    const float* wp = Wo + (size_t)n * 512 + h * 64;
#pragma unroll
    for (int jc = 0; jc < 16; ++jc) w[jc] = *(const float4*)(wp + jc * 4);
    __syncthreads();

    for (int u = 0; u < U_; ++u) {
        float acc = 0.f;
#pragma unroll
        for (int jc = 0; jc < 16; ++jc) {
            float4 dv = *(const float4*)&sd[u][jc * 4];
            acc = fmaf(dv.w, w[jc].w, fmaf(dv.z, w[jc].z,
                  fmaf(dv.y, w[jc].y, fmaf(dv.x, w[jc].x, acc))));
        }
        atomicAdd(out + ((size_t)b * L_ + ls[u]) * 512 + n, acc);
    }
}

// ---------------------------------------------------------------
extern "C" void kernel_launch(void* const* d_in, const int* in_sizes, int n_in,
                              void* d_out, int out_size, void* d_ws, size_t ws_size,
                              hipStream_t stream)
{
    (void)in_sizes; (void)n_in; (void)out_size; (void)ws_size;
    const float* query = (const float*)d_in[0];
    const float* key   = (const float*)d_in[1];
    const float* value = (const float*)d_in[2];
    const int*   mask  = (const int*)d_in[3];
    const float* Wq = (const float*)d_in[4];
    const float* bq = (const float*)d_in[5];
    const float* Wk = (const float*)d_in[6];
    const float* bk = (const float*)d_in[7];
    const float* Wv = (const float*)d_in[8];
    const float* bvp = (const float*)d_in[9];
    const float* Wo = (const float*)d_in[10];
    const float* bo = (const float*)d_in[11];
    float* out = (float*)d_out;

    float* ws = (float*)d_ws;
    float* v      = ws + OFF_V;
    unsigned short* q_hi = (unsigned short*)(ws + OFF_QHI);
    unsigned short* q_lo = (unsigned short*)(ws + OFF_QLO);
    unsigned short* k_hi = (unsigned short*)(ws + OFF_KHI);
    unsigned short* k_lo = (unsigned short*)(ws + OFF_KLO);
    float* ctxp   = ws + OFF_CTXP;
    float* S      = ws + OFF_S;
    float* Marr   = ws + OFF_M;
    float* kmean  = ws + OFF_KMEAN;
    float* vmean  = ws + OFF_VMEAN;
    float* ctxd   = ws + OFF_CTXD;
    int*   idx    = (int*)(ws + OFF_IDX);
    float* obase  = ws + OFF_OBASE;
    unsigned short* wqh = (unsigned short*)(ws + OFF_WQH);
    unsigned short* wql = (unsigned short*)(ws + OFF_WQL);
    unsigned short* wkh = (unsigned short*)(ws + OFF_WKH);
    unsigned short* wkl = (unsigned short*)(ws + OFF_WKL);
    unsigned short* wvh = (unsigned short*)(ws + OFF_WVH);
    unsigned short* wvl = (unsigned short*)(ws + OFF_WVL);

    // weight splits (fused)
    split_w3<<<3072, 256, 0, stream>>>(Wq, Wk, Wv, wqh, wql, wkh, wkl, wvh, wvl);

    // projections (bf16x2 MFMA); q,k emit hi/lo bf16, v emits fp32
    const dim3 ggemm(128, 4);
    gemm_mfma<<<ggemm, 256, 0, stream>>>(query, wqh, wql, bq, nullptr, q_hi, q_lo, 1);
    gemm_mfma<<<ggemm, 256, 0, stream>>>(key,   wkh, wkl, bk, nullptr, k_hi, k_lo, 1);
    gemm_mfma<<<ggemm, 256, 0, stream>>>(value, wvh, wvl, bvp, v, nullptr, nullptr, 1);

    // per-(b,h) means (fused) + base output row
    means_fused<<<256, 256, 0, stream>>>(k_hi, k_lo, v, kmean, vmean);
    vmean_proj<<<128, 256, 0, stream>>>(vmean, Wo, bo, obase);

    // sparsity measure M (MFMA, XCD-swizzled grid) and top-35
    qk_rowmax_mfma<<<dim3(128, 16), 256, 0, stream>>>(q_hi, q_lo, k_hi, k_lo, kmean, Marr);
    topk35<<<128, 256, 0, stream>>>(Marr, idx);

    // reduced attention (K-split for parallelism)
    scores_red<<<dim3(128, 8), 256, 0, stream>>>(q_hi, q_lo, k_hi, k_lo, idx, mask, S);
    softmax_rows<<<B_ * H_ * U_, 256, 0, stream>>>(S);
    ctx_partial<<<dim3(128, 8), 256, 0, stream>>>(S, v, ctxp);   // ctxp aliases q_hi (dead)
    ctx_reduce_diff<<<1120, 256, 0, stream>>>(ctxp, vmean, ctxd);

    // output = broadcast base row + sparse delta (replaces full Wo GEMM)
    broadcast_out<<<8192, 256, 0, stream>>>(obase, out);
    delta_out<<<dim3(128, 4), 128, 0, stream>>>(ctxd, idx, Wo, out);
}

// Round 8
// 467.733 us; speedup vs baseline: 1.1344x; 1.0189x over previous
//
#include <hip/hip_runtime.h>
#include <math.h>

#define B_ 16
#define L_ 1024
#define H_ 8
#define U_ 35

typedef float f32x4 __attribute__((ext_vector_type(4)));
typedef short bf16x8 __attribute__((ext_vector_type(8)));

__device__ __forceinline__ unsigned short f2bf(float x) {
    unsigned int u = __float_as_uint(x);
    u += 0x7FFFu + ((u >> 16) & 1u);      // round-to-nearest-even
    return (unsigned short)(u >> 16);
}
__device__ __forceinline__ float bf2f(unsigned short b) {
    return __uint_as_float(((unsigned int)b) << 16);
}

#define MFMA(a, b, c) __builtin_amdgcn_mfma_f32_16x16x32_bf16((a), (b), (c), 0, 0, 0)

// ---------------- workspace layout (float-element offsets) ----------------
#define OFF_V      ((size_t)0)           // 8388608 f
#define OFF_QHI    ((size_t)8388608)     // 4194304
#define OFF_QLO    ((size_t)12582912)    // 4194304
#define OFF_CTXP   OFF_QHI               // ctx partials alias q_hi (dead after scores)
#define OFF_KHI    ((size_t)16777216)    // 4194304
#define OFF_KLO    ((size_t)20971520)    // 4194304
#define OFF_S      ((size_t)25165824)    // 4587520
#define OFF_WQH    OFF_S                 // W splits alias S (dead before scores)
#define OFF_WQL    ((size_t)(OFF_S + 131072))
#define OFF_WKH    ((size_t)(OFF_S + 262144))
#define OFF_WKL    ((size_t)(OFF_S + 393216))
#define OFF_WVH    ((size_t)(OFF_S + 524288))
#define OFF_WVL    ((size_t)(OFF_S + 655360))
#define OFF_M      ((size_t)29753344)    // 131072
#define OFF_KMEAN  ((size_t)29884416)    // 8192
#define OFF_VMEAN  ((size_t)29892608)    // 8192
#define OFF_CTXD   ((size_t)29900800)    // 286720 (ctx - vmean diffs)
#define OFF_IDX    ((size_t)30187520)    // 4480
#define OFF_OBASE  ((size_t)30192000)    // 8192 (per-b base output row)
// end ~30.2M f = ~121 MB

// ---------------------------------------------------------------
// split Wq/Wk/Wv fp32 -> hi/lo bf16; grid 3072 x 256
// ---------------------------------------------------------------
__global__ __launch_bounds__(256) void split_w3(
    const float* __restrict__ Wq, const float* __restrict__ Wk,
    const float* __restrict__ Wv,
    unsigned short* __restrict__ wqh, unsigned short* __restrict__ wql,
    unsigned short* __restrict__ wkh, unsigned short* __restrict__ wkl,
    unsigned short* __restrict__ wvh, unsigned short* __restrict__ wvl)
{
    const int w = blockIdx.x >> 10;
    const int i = (blockIdx.x & 1023) * 256 + threadIdx.x;
    const float* W = (w == 0) ? Wq : (w == 1) ? Wk : Wv;
    unsigned short* hi = (w == 0) ? wqh : (w == 1) ? wkh : wvh;
    unsigned short* lo = (w == 0) ? wql : (w == 1) ? wkl : wvl;
    float x = W[i];
    unsigned short h = f2bf(x);
    hi[i] = h;
    lo[i] = f2bf(x - bf2f(h));
}

// ---------------------------------------------------------------
// bf16x2 MFMA GEMM: C[m,n] = sum_k A[m,k]*W[n,k] + bias[n]
// ---------------------------------------------------------------
__global__ __launch_bounds__(256) void gemm_mfma(
    const float* __restrict__ A,
    const unsigned short* __restrict__ Whi, const unsigned short* __restrict__ Wlo,
    const float* __restrict__ bias,
    float* __restrict__ outf,
    unsigned short* __restrict__ ohi, unsigned short* __restrict__ olo,
    const int head_layout)
{
    __shared__ unsigned short Ah[128][40];
    __shared__ unsigned short Al[128][40];
    __shared__ unsigned short Bh[128][40];
    __shared__ unsigned short Bl[128][40];
    const int tid = threadIdx.x, lane = tid & 63, wave = tid >> 6;
    const int m0 = blockIdx.x * 128, n0 = blockIdx.y * 128;
    const int wm = (wave >> 1) * 64, wn = (wave & 1) * 64;

    f32x4 zero4 = {0.f, 0.f, 0.f, 0.f};
    f32x4 acc[4][4];
#pragma unroll
    for (int i = 0; i < 4; i++)
#pragma unroll
        for (int j = 0; j < 4; j++) acc[i][j] = zero4;

    const int ar = tid >> 3, ac = (tid & 7) * 4;
    const int br = tid >> 2, bc = (tid & 3) * 8;
    const int kc = (lane >> 4) * 8;
    const int fr = lane & 15;

    for (int k0 = 0; k0 < 512; k0 += 32) {
        if (k0) __syncthreads();
#pragma unroll
        for (int p = 0; p < 4; ++p) {
            float4 a4 = *(const float4*)(A + (size_t)(m0 + ar + p * 32) * 512 + k0 + ac);
            ushort4 h4, l4;
            h4.x = f2bf(a4.x); l4.x = f2bf(a4.x - bf2f(h4.x));
            h4.y = f2bf(a4.y); l4.y = f2bf(a4.y - bf2f(h4.y));
            h4.z = f2bf(a4.z); l4.z = f2bf(a4.z - bf2f(h4.z));
            h4.w = f2bf(a4.w); l4.w = f2bf(a4.w - bf2f(h4.w));
            *(ushort4*)&Ah[ar + p * 32][ac] = h4;
            *(ushort4*)&Al[ar + p * 32][ac] = l4;
        }
#pragma unroll
        for (int p = 0; p < 2; ++p) {
            size_t off = (size_t)(n0 + br + p * 64) * 512 + k0 + bc;
            *(uint4*)&Bh[br + p * 64][bc] = *(const uint4*)(Whi + off);
            *(uint4*)&Bl[br + p * 64][bc] = *(const uint4*)(Wlo + off);
        }
        __syncthreads();

        bf16x8 ah[4], al[4];
#pragma unroll
        for (int mi = 0; mi < 4; ++mi) {
            int row = wm + mi * 16 + fr;
            ah[mi] = *(bf16x8*)&Ah[row][kc];
            al[mi] = *(bf16x8*)&Al[row][kc];
        }
#pragma unroll
        for (int ni = 0; ni < 4; ++ni) {
            int rn = wn + ni * 16 + fr;
            bf16x8 bh8 = *(bf16x8*)&Bh[rn][kc];
            bf16x8 bl8 = *(bf16x8*)&Bl[rn][kc];
#pragma unroll
            for (int mi = 0; mi < 4; ++mi) {
                acc[mi][ni] = MFMA(ah[mi], bh8, acc[mi][ni]);
                acc[mi][ni] = MFMA(ah[mi], bl8, acc[mi][ni]);
                acc[mi][ni] = MFMA(al[mi], bh8, acc[mi][ni]);
            }
        }
    }

    const int col = lane & 15, rq = (lane >> 4) * 4;
#pragma unroll
    for (int ni = 0; ni < 4; ++ni) {
        int n = n0 + wn + ni * 16 + col;
        float bn = bias[n];
#pragma unroll
        for (int mi = 0; mi < 4; ++mi) {
#pragma unroll
            for (int r = 0; r < 4; ++r) {
                int m = m0 + wm + mi * 16 + rq + r;
                float val = acc[mi][ni][r] + bn;
                if (head_layout) {
                    size_t off = ((size_t)((m >> 10) * H_ + (n >> 6)) * L_ + (m & 1023)) * 64 + (n & 63);
                    if (outf) outf[off] = val;
                    if (ohi) {
                        unsigned short h = f2bf(val);
                        ohi[off] = h;
                        olo[off] = f2bf(val - bf2f(h));
                    }
                } else {
                    outf[(size_t)m * 512 + n] = val;
                }
            }
        }
    }
}

// ---------------------------------------------------------------
// fused means: blocks 0..127 -> kmean (from k hi/lo), 128..255 -> vmean (fp32)
// ---------------------------------------------------------------
__global__ __launch_bounds__(256) void means_fused(
    const unsigned short* __restrict__ khi, const unsigned short* __restrict__ klo,
    const float* __restrict__ v, float* __restrict__ kmean, float* __restrict__ vmean)
{
    const int which = blockIdx.x >> 7;
    const int bh = blockIdx.x & 127;
    const int d = threadIdx.x & 63, g = threadIdx.x >> 6;
    __shared__ float red[4][64];
    float s = 0.f;
    if (which == 0) {
        size_t base = ((size_t)bh * L_ + g * 256) * 64 + d;
#pragma unroll 8
        for (int l = 0; l < 256; l++) {
            size_t o = base + (size_t)l * 64;
            s += bf2f(khi[o]) + bf2f(klo[o]);
        }
    } else {
        const float* p = v + ((size_t)bh * L_ + g * 256) * 64 + d;
#pragma unroll 8
        for (int l = 0; l < 256; l++) s += p[(size_t)l * 64];
    }
    red[g][d] = s;
    __syncthreads();
    if (threadIdx.x < 64) {
        const int dd = threadIdx.x;
        float m = (red[0][dd] + red[1][dd] + red[2][dd] + red[3][dd]) * (1.0f / 1024.0f);
        (which == 0 ? kmean : vmean)[(size_t)bh * 64 + dd] = m;
    }
}

// ---------------------------------------------------------------
// M[l] = max_k(q_l . k_k) - q_l . kmean via bf16x2 MFMA
// grid (128 bh, 16 qt): XCD-local K reuse (bh%8 pins the XCD).
// Q fragments hoisted to registers (loop-invariant); 64-row K tiles
// (16 kt) cut LDS to ~38 KB for 3-4 blocks/CU occupancy.
// ---------------------------------------------------------------
__global__ __launch_bounds__(256) void qk_rowmax_mfma(
    const unsigned short* __restrict__ qhi, const unsigned short* __restrict__ qlo,
    const unsigned short* __restrict__ khi, const unsigned short* __restrict__ klo,
    const float* __restrict__ kmean, float* __restrict__ Mout)
{
    __shared__ unsigned short Qh[64][72], Ql[64][72];
    __shared__ unsigned short Kh[64][72], Kl[64][72];
    __shared__ float Mred[64][4];
    __shared__ float km[64];
    const int bh = blockIdx.x, q0 = blockIdx.y * 64;
    const int tid = threadIdx.x, lane = tid & 63, wave = tid >> 6;

    if (tid < 64) km[tid] = kmean[bh * 64 + tid];
    {
        int r = tid >> 2, c = (tid & 3) * 16;
        size_t off = ((size_t)bh * L_ + q0 + r) * 64 + c;
        *(uint4*)&Qh[r][c]     = *(const uint4*)(qhi + off);
        *(uint4*)&Qh[r][c + 8] = *(const uint4*)(qhi + off + 8);
        *(uint4*)&Ql[r][c]     = *(const uint4*)(qlo + off);
        *(uint4*)&Ql[r][c + 8] = *(const uint4*)(qlo + off + 8);
    }

    const size_t kb = (size_t)bh * L_ * 64;
    const int sr = tid >> 2, sc = (tid & 3) * 16;
    const int fr = lane & 15;
    f32x4 zero4 = {0.f, 0.f, 0.f, 0.f};

    // register prefetch of K tile 0 (64 rows)
    uint4 pha, phb, pla, plb;
    {
        size_t off = kb + (size_t)sr * 64 + sc;
        pha = *(const uint4*)(khi + off);  phb = *(const uint4*)(khi + off + 8);
        pla = *(const uint4*)(klo + off);  plb = *(const uint4*)(klo + off + 8);
    }

    __syncthreads();   // Q/km staged

    // hoist Q fragments into registers — invariant across the K loop
    bf16x8 qah[2][4], qal[2][4];
#pragma unroll
    for (int ks = 0; ks < 2; ++ks) {
        int kcol = ks * 32 + (lane >> 4) * 8;
#pragma unroll
        for (int mi = 0; mi < 4; ++mi) {
            qah[ks][mi] = *(bf16x8*)&Qh[mi * 16 + fr][kcol];
            qal[ks][mi] = *(bf16x8*)&Ql[mi * 16 + fr][kcol];
        }
    }

    float rmax[4][4];
#pragma unroll
    for (int mi = 0; mi < 4; ++mi)
#pragma unroll
        for (int r = 0; r < 4; ++r) rmax[mi][r] = -INFINITY;

    for (int kt = 0; kt < 16; ++kt) {
        if (kt) __syncthreads();   // previous tile's readers done
        *(uint4*)&Kh[sr][sc] = pha;  *(uint4*)&Kh[sr][sc + 8] = phb;
        *(uint4*)&Kl[sr][sc] = pla;  *(uint4*)&Kl[sr][sc + 8] = plb;
        __syncthreads();

        if (kt < 15) {   // next-tile loads drain behind the MFMAs
            size_t off = kb + (size_t)((kt + 1) * 64 + sr) * 64 + sc;
            pha = *(const uint4*)(khi + off);  phb = *(const uint4*)(khi + off + 8);
            pla = *(const uint4*)(klo + off);  plb = *(const uint4*)(klo + off + 8);
        }

        f32x4 acc[4];
#pragma unroll
        for (int mi = 0; mi < 4; ++mi) acc[mi] = zero4;

#pragma unroll
        for (int ks = 0; ks < 2; ++ks) {
            int kcol = ks * 32 + (lane >> 4) * 8;
            int krow = wave * 16 + fr;
            bf16x8 bh8 = *(bf16x8*)&Kh[krow][kcol];
            bf16x8 bl8 = *(bf16x8*)&Kl[krow][kcol];
#pragma unroll
            for (int mi = 0; mi < 4; ++mi) {
                acc[mi] = MFMA(qah[ks][mi], bh8, acc[mi]);
                acc[mi] = MFMA(qah[ks][mi], bl8, acc[mi]);
                acc[mi] = MFMA(qal[ks][mi], bh8, acc[mi]);
            }
        }
#pragma unroll
        for (int mi = 0; mi < 4; ++mi)
#pragma unroll
            for (int r = 0; r < 4; ++r)
                rmax[mi][r] = fmaxf(rmax[mi][r], acc[mi][r]);
    }

    // reduce over the 16 k-columns held across lanes of each 16-group
#pragma unroll
    for (int mi = 0; mi < 4; ++mi)
#pragma unroll
        for (int r = 0; r < 4; ++r) {
            float v = rmax[mi][r];
            v = fmaxf(v, __shfl_xor(v, 1));
            v = fmaxf(v, __shfl_xor(v, 2));
            v = fmaxf(v, __shfl_xor(v, 4));
            v = fmaxf(v, __shfl_xor(v, 8));
            rmax[mi][r] = v;
        }
    if ((lane & 15) == 0) {
        int quad = lane >> 4;
#pragma unroll
        for (int mi = 0; mi < 4; ++mi)
#pragma unroll
            for (int r = 0; r < 4; ++r)
                Mred[mi * 16 + quad * 4 + r][wave] = rmax[mi][r];
    }
    __syncthreads();
    if (tid < 64) {
        float mx = fmaxf(fmaxf(Mred[tid][0], Mred[tid][1]),
                         fmaxf(Mred[tid][2], Mred[tid][3]));
        float dot = 0.f;
#pragma unroll 4
        for (int d = 0; d < 64; ++d)
            dot = fmaf(bf2f(Qh[tid][d]) + bf2f(Ql[tid][d]), km[d], dot);
        Mout[(size_t)bh * L_ + q0 + tid] = mx - dot;
    }
}

// ---------------------------------------------------------------
// top-35 of M[1024] per (b,h)
// ---------------------------------------------------------------
__global__ __launch_bounds__(256) void topk35(
    const float* __restrict__ Min, int* __restrict__ idx_out)
{
    const int bh = blockIdx.x;
    const int tid = threadIdx.x;
    __shared__ float vals[1024];
    __shared__ float wv[4];
    __shared__ int wi[4];
    for (int i = tid; i < 1024; i += 256) vals[i] = Min[(size_t)bh * 1024 + i];
    __syncthreads();
    for (int it = 0; it < U_; ++it) {
        float bv = -INFINITY; int bi = 1 << 30;
        for (int i = tid; i < 1024; i += 256) {
            float x = vals[i];
            if (x > bv) { bv = x; bi = i; }
        }
#pragma unroll
        for (int off = 32; off; off >>= 1) {
            float ov = __shfl_down(bv, off);
            int   oi = __shfl_down(bi, off);
            if (ov > bv || (ov == bv && oi < bi)) { bv = ov; bi = oi; }
        }
        if ((tid & 63) == 0) { wv[tid >> 6] = bv; wi[tid >> 6] = bi; }
        __syncthreads();
        if (tid == 0) {
#pragma unroll
            for (int w = 1; w < 4; ++w) {
                if (wv[w] > bv || (wv[w] == bv && wi[w] < bi)) { bv = wv[w]; bi = wi[w]; }
            }
            idx_out[bh * U_ + it] = bi;
            vals[bi] = -INFINITY;
        }
        __syncthreads();
    }
}

// ---------------------------------------------------------------
// S[u][k] = (q[idx_u] . k_k)/8 masked; grid (128 bh, 8 key-chunks)
// ---------------------------------------------------------------
__global__ __launch_bounds__(256) void scores_red(
    const unsigned short* __restrict__ qhi, const unsigned short* __restrict__ qlo,
    const unsigned short* __restrict__ khi, const unsigned short* __restrict__ klo,
    const int* __restrict__ idx, const int* __restrict__ mask,
    float* __restrict__ S)
{
    __shared__ float Qs[64][36];
    __shared__ float Ks[64][68];
    const int bh = blockIdx.x;
    const int b = bh >> 3;
    const int tid = threadIdx.x;
    const int tk = tid & 63, tg = tid >> 6;

    for (int t = tid; t < 36 * 64; t += 256) {
        int u = t >> 6, d = t & 63;
        float val = 0.f;
        if (u < U_) {
            int l = idx[bh * U_ + u];
            size_t off = ((size_t)bh * L_ + l) * 64 + d;
            val = bf2f(qhi[off]) + bf2f(qlo[off]);
        }
        Qs[d][u] = val;
    }

    const size_t kb = (size_t)bh * L_ * 64;
    const int sr = tid >> 2, sc = (tid & 3) * 16;
    float acc[9];
    const int kt0 = blockIdx.y * 2;
    for (int ki = 0; ki < 2; ++ki) {
        int kt = kt0 + ki;
        if (ki) __syncthreads();
        {
            size_t off = kb + (size_t)(kt * 64 + sr) * 64 + sc;
            uint4 h0 = *(const uint4*)(khi + off);
            uint4 h1 = *(const uint4*)(khi + off + 8);
            uint4 l0 = *(const uint4*)(klo + off);
            uint4 l1 = *(const uint4*)(klo + off + 8);
            unsigned short hv[16], lv[16];
            *(uint4*)hv = h0; *(uint4*)(hv + 8) = h1;
            *(uint4*)lv = l0; *(uint4*)(lv + 8) = l1;
#pragma unroll
            for (int i = 0; i < 16; ++i)
                Ks[sc + i][sr] = bf2f(hv[i]) + bf2f(lv[i]);
        }
        __syncthreads();
#pragma unroll
        for (int j = 0; j < 9; j++) acc[j] = 0.f;
#pragma unroll 4
        for (int d = 0; d < 64; ++d) {
            float kv = Ks[d][tk];
#pragma unroll
            for (int j = 0; j < 9; j++) acc[j] = fmaf(Qs[d][tg + 4 * j], kv, acc[j]);
        }
        const int kcol = kt * 64 + tk;
        const bool msk = (mask[b * L_ + kcol] == 0);
#pragma unroll
        for (int j = 0; j < 9; j++) {
            int u = tg + 4 * j;
            if (u < U_)
                S[((size_t)bh * U_ + u) * 1024 + kcol] = msk ? -INFINITY : acc[j] * 0.125f;
        }
    }
}

// ---------------------------------------------------------------
// softmax over 1024 per row; grid 4480 rows
// ---------------------------------------------------------------
__global__ __launch_bounds__(256) void softmax_rows(float* __restrict__ S)
{
    const size_t base = (size_t)blockIdx.x * 1024;
    const int tid = threadIdx.x;
    __shared__ float redm[4];
    __shared__ float reds[4];
    float4 v = *(const float4*)(S + base + tid * 4);
    float mx = fmaxf(fmaxf(v.x, v.y), fmaxf(v.z, v.w));
#pragma unroll
    for (int off = 32; off; off >>= 1) mx = fmaxf(mx, __shfl_down(mx, off));
    if ((tid & 63) == 0) redm[tid >> 6] = mx;
    __syncthreads();
    mx = fmaxf(fmaxf(redm[0], redm[1]), fmaxf(redm[2], redm[3]));
    float e0 = __expf(v.x - mx), e1 = __expf(v.y - mx);
    float e2 = __expf(v.z - mx), e3 = __expf(v.w - mx);
    float s = e0 + e1 + e2 + e3;
#pragma unroll
    for (int off = 32; off; off >>= 1) s += __shfl_down(s, off);
    if ((tid & 63) == 0) reds[tid >> 6] = s;
    __syncthreads();
    s = reds[0] + reds[1] + reds[2] + reds[3];
    const float inv = 1.0f / s;
    float4 o; o.x = e0 * inv; o.y = e1 * inv; o.z = e2 * inv; o.w = e3 * inv;
    *(float4*)(S + base + tid * 4) = o;
}

// ---------------------------------------------------------------
// ctx partials: grid (128 bh, 8 kc)
// ---------------------------------------------------------------
__global__ __launch_bounds__(256) void ctx_partial(
    const float* __restrict__ S, const float* __restrict__ v,
    float* __restrict__ ctxp)
{
    __shared__ float Vs[128][68];
    __shared__ float Wt[36][128];
    const int bh = blockIdx.x, kc = blockIdx.y;
    const int tid = threadIdx.x;
    const int td = tid & 63, tg = tid >> 6;
    const int lr = tid >> 2, lc0 = (tid & 3) * 16;

    const float* vbase = v + ((size_t)bh * L_ + kc * 128) * 64;
    const float* Sbase = S + (size_t)bh * U_ * 1024 + kc * 128;

#pragma unroll
    for (int hh = 0; hh < 2; ++hh) {
        int row = lr + hh * 64;
        const float* src = vbase + (size_t)row * 64 + lc0;
        *(float4*)&Vs[row][lc0 + 0]  = *(const float4*)(src + 0);
        *(float4*)&Vs[row][lc0 + 4]  = *(const float4*)(src + 4);
        *(float4*)&Vs[row][lc0 + 8]  = *(const float4*)(src + 8);
        *(float4*)&Vs[row][lc0 + 12] = *(const float4*)(src + 12);
    }
    for (int t = tid; t < 36 * 128; t += 256) {
        int u = t >> 7, kk = t & 127;
        Wt[u][kk] = (u < U_) ? Sbase[(size_t)u * 1024 + kk] : 0.f;
    }
    __syncthreads();

    float acc[9];
#pragma unroll
    for (int j = 0; j < 9; j++) acc[j] = 0.f;
#pragma unroll 2
    for (int kk = 0; kk < 128; ++kk) {
        float vv = Vs[kk][td];
#pragma unroll
        for (int j = 0; j < 9; j++) acc[j] = fmaf(Wt[tg + 4 * j][kk], vv, acc[j]);
    }
#pragma unroll
    for (int j = 0; j < 9; j++) {
        int u = tg + 4 * j;
        if (u < U_)
            ctxp[((size_t)(kc * 128 + bh) * 36 + u) * 64 + td] = acc[j];
    }
}

// ---------------------------------------------------------------
// ctxd[bh][u][d] = sum_kc ctxp - vmean[bh][d] ; grid 1120 x 256
// ---------------------------------------------------------------
__global__ __launch_bounds__(256) void ctx_reduce_diff(
    const float* __restrict__ ctxp, const float* __restrict__ vmean,
    float* __restrict__ ctxd)
{
    const int i = blockIdx.x * 256 + threadIdx.x;   // 128*35*64 = 286720
    const int d = i & 63;
    const int rest = i >> 6;
    const int u = rest % U_;
    const int bh = rest / U_;
    float s = 0.f;
#pragma unroll
    for (int kc = 0; kc < 8; ++kc)
        s += ctxp[((size_t)(kc * 128 + bh) * 36 + u) * 64 + d];
    ctxd[i] = s - vmean[(size_t)bh * 64 + d];
}

// ---------------------------------------------------------------
// obase[b][n] = dot(xbar[b], Wo[n]) + bo[n] ; grid 128 (16 b x 8 nchunk)
// ---------------------------------------------------------------
__global__ __launch_bounds__(256) void vmean_proj(
    const float* __restrict__ vmean, const float* __restrict__ Wo,
    const float* __restrict__ bo, float* __restrict__ obase)
{
    const int b = blockIdx.x >> 3, n0 = (blockIdx.x & 7) * 64;
    const int tid = threadIdx.x;
    __shared__ float xbar[512];
    __shared__ float psum[64][5];
    for (int i = tid; i < 512; i += 256)
        xbar[i] = vmean[(size_t)(b * 8 + (i >> 6)) * 64 + (i & 63)];
    __syncthreads();
    const int n = n0 + (tid >> 2), fq = (tid & 3) * 128;
    float s = 0.f;
    for (int f = 0; f < 128; f += 4) {
        float4 w = *(const float4*)(Wo + (size_t)n * 512 + fq + f);
        s += xbar[fq + f] * w.x + xbar[fq + f + 1] * w.y +
             xbar[fq + f + 2] * w.z + xbar[fq + f + 3] * w.w;
    }
    psum[tid >> 2][tid & 3] = s;
    __syncthreads();
    if (tid < 64)
        obase[(size_t)b * 512 + n0 + tid] =
            psum[tid][0] + psum[tid][1] + psum[tid][2] + psum[tid][3] + bo[n0 + tid];
}

// ---------------------------------------------------------------
// out[b][l][:] = obase[b][:] ; grid 8192 x 256 (float4)
// ---------------------------------------------------------------
__global__ void broadcast_out(const float* __restrict__ obase, float* __restrict__ out)
{
    const size_t e = ((size_t)blockIdx.x * 256 + threadIdx.x) * 4;
    const int n = (int)(e & 511);
    const int b = (int)(e >> 19);
    *(float4*)(out + e) = *(const float4*)(obase + (b << 9) + n);
}

// ---------------------------------------------------------------
// out[b][l_u][n] += ctxd[bh][u] . Wo[n][h*64..]
// grid (128 bh, 4 col-chunks) x 128 threads; one column n per thread.
// ---------------------------------------------------------------
__global__ __launch_bounds__(128) void delta_out(
    const float* __restrict__ ctxd, const int* __restrict__ idx,
    const float* __restrict__ Wo, float* __restrict__ out)
{
    const int bh = blockIdx.x, b = bh >> 3, h = bh & 7;
    const int tid = threadIdx.x;
    const int n = blockIdx.y * 128 + tid;
    __shared__ float sd[U_][64];
    __shared__ int ls[U_];
    if (tid < U_) ls[tid] = idx[bh * U_ + tid];
    for (int t = tid; t < U_ * 64; t += 128)
        sd[t >> 6][t & 63] = ctxd[(size_t)bh * U_ * 64 + t];

    float4 w[16];
    const float* wp = Wo + (size_t)n * 512 + h * 64;
#pragma unroll
    for (int jc = 0; jc < 16; ++jc) w[jc] = *(const float4*)(wp + jc * 4);
    __syncthreads();

    for (int u = 0; u < U_; ++u) {
        float acc = 0.f;
#pragma unroll
        for (int jc = 0; jc < 16; ++jc) {
            float4 dv = *(const float4*)&sd[u][jc * 4];
            acc = fmaf(dv.w, w[jc].w, fmaf(dv.z, w[jc].z,
                  fmaf(dv.y, w[jc].y, fmaf(dv.x, w[jc].x, acc))));
        }
        atomicAdd(out + ((size_t)b * L_ + ls[u]) * 512 + n, acc);
    }
}

// ---------------------------------------------------------------
extern "C" void kernel_launch(void* const* d_in, const int* in_sizes, int n_in,
                              void* d_out, int out_size, void* d_ws, size_t ws_size,
                              hipStream_t stream)
{
    (void)in_sizes; (void)n_in; (void)out_size; (void)ws_size;
    const float* query = (const float*)d_in[0];
    const float* key   = (const float*)d_in[1];
    const float* value = (const float*)d_in[2];
    const int*   mask  = (const int*)d_in[3];
    const float* Wq = (const float*)d_in[4];
    const float* bq = (const float*)d_in[5];
    const float* Wk = (const float*)d_in[6];
    const float* bk = (const float*)d_in[7];
    const float* Wv = (const float*)d_in[8];
    const float* bvp = (const float*)d_in[9];
    const float* Wo = (const float*)d_in[10];
    const float* bo = (const float*)d_in[11];
    float* out = (float*)d_out;

    float* ws = (float*)d_ws;
    float* v      = ws + OFF_V;
    unsigned short* q_hi = (unsigned short*)(ws + OFF_QHI);
    unsigned short* q_lo = (unsigned short*)(ws + OFF_QLO);
    unsigned short* k_hi = (unsigned short*)(ws + OFF_KHI);
    unsigned short* k_lo = (unsigned short*)(ws + OFF_KLO);
    float* ctxp   = ws + OFF_CTXP;
    float* S      = ws + OFF_S;
    float* Marr   = ws + OFF_M;
    float* kmean  = ws + OFF_KMEAN;
    float* vmean  = ws + OFF_VMEAN;
    float* ctxd   = ws + OFF_CTXD;
    int*   idx    = (int*)(ws + OFF_IDX);
    float* obase  = ws + OFF_OBASE;
    unsigned short* wqh = (unsigned short*)(ws + OFF_WQH);
    unsigned short* wql = (unsigned short*)(ws + OFF_WQL);
    unsigned short* wkh = (unsigned short*)(ws + OFF_WKH);
    unsigned short* wkl = (unsigned short*)(ws + OFF_WKL);
    unsigned short* wvh = (unsigned short*)(ws + OFF_WVH);
    unsigned short* wvl = (unsigned short*)(ws + OFF_WVL);

    // weight splits (fused)
    split_w3<<<3072, 256, 0, stream>>>(Wq, Wk, Wv, wqh, wql, wkh, wkl, wvh, wvl);

    // projections (bf16x2 MFMA); q,k emit hi/lo bf16, v emits fp32
    const dim3 ggemm(128, 4);
    gemm_mfma<<<ggemm, 256, 0, stream>>>(query, wqh, wql, bq, nullptr, q_hi, q_lo, 1);
    gemm_mfma<<<ggemm, 256, 0, stream>>>(key,   wkh, wkl, bk, nullptr, k_hi, k_lo, 1);
    gemm_mfma<<<ggemm, 256, 0, stream>>>(value, wvh, wvl, bvp, v, nullptr, nullptr, 1);

    // per-(b,h) means (fused) + base output row
    means_fused<<<256, 256, 0, stream>>>(k_hi, k_lo, v, kmean, vmean);
    vmean_proj<<<128, 256, 0, stream>>>(vmean, Wo, bo, obase);

    // sparsity measure M (MFMA, XCD-swizzled, hoisted-Q, 64-row tiles)
    qk_rowmax_mfma<<<dim3(128, 16), 256, 0, stream>>>(q_hi, q_lo, k_hi, k_lo, kmean, Marr);
    topk35<<<128, 256, 0, stream>>>(Marr, idx);

    // reduced attention (K-split for parallelism)
    scores_red<<<dim3(128, 8), 256, 0, stream>>>(q_hi, q_lo, k_hi, k_lo, idx, mask, S);
    softmax_rows<<<B_ * H_ * U_, 256, 0, stream>>>(S);
    ctx_partial<<<dim3(128, 8), 256, 0, stream>>>(S, v, ctxp);   // ctxp aliases q_hi (dead)
    ctx_reduce_diff<<<1120, 256, 0, stream>>>(ctxp, vmean, ctxd);

    // output = broadcast base row + sparse delta (replaces full Wo GEMM)
    broadcast_out<<<8192, 256, 0, stream>>>(obase, out);
    delta_out<<<dim3(128, 4), 128, 0, stream>>>(ctxd, idx, Wo, out);
}